// Round 1
// baseline (933.391 us; speedup 1.0000x reference)
//
#include <hip/hip_runtime.h>
#include <math.h>

// TinyMoE: B=8192 tokens, H=1024, E=8 experts, top_k=2.
// Sparse top-2 MoE: router -> per-expert token lists -> split-bf16 (hi+lo, 3-pass)
// MFMA GEMMs for fp32-grade accuracy at matrix-core rate -> combine.
// Outputs: combined [B,H] fp32 at d_out[0], weights [B,E] fp32 at d_out[B*H].
//
// ws layout (~202 MB): cnt | list | wlist | W1^T hi/lo | W2^T hi/lo | H1 hi/lo | OUTC

#define HB 1024
#define NB 8192
#define NE 8

#define BM 128
#define BN 128
#define BK 64
#define PK 72   // padded LDS row stride in shorts (144B: 16B-aligned, 4-bank skew per row)

typedef unsigned short ushort_t;
typedef __attribute__((ext_vector_type(8))) short bfx8;
typedef __attribute__((ext_vector_type(4))) float f32x4;

__device__ __forceinline__ ushort_t f2bf(float f) {
  unsigned int x = __float_as_uint(f);
  x += 0x7fffu + ((x >> 16) & 1u);   // RTNE
  return (ushort_t)(x >> 16);
}
__device__ __forceinline__ float bf2f(ushort_t h) {
  return __uint_as_float(((unsigned int)h) << 16);
}
__device__ __forceinline__ float gelu_exact(float x) {
  return 0.5f * x * (1.0f + erff(x * 0.70710678118654752440f));
}

// ---------------- zero counts ----------------
__global__ void zero_cnt_kernel(int* cnt) {
  if (threadIdx.x < NE) cnt[threadIdx.x] = 0;
}

// ---------------- W transpose + bf16 hi/lo split ----------------
// W[e][k][n] fp32  ->  T[e][n][k] bf16 hi and lo arrays (so B-fragments read contiguous K).
__global__ __launch_bounds__(256) void wsplit_kernel(
    const float* __restrict__ W1, const float* __restrict__ W2,
    ushort_t* __restrict__ T1h, ushort_t* __restrict__ T1l,
    ushort_t* __restrict__ T2h, ushort_t* __restrict__ T2l)
{
  __shared__ float sT[32][33];
  const int e = blockIdx.z >> 1;
  const int which = blockIdx.z & 1;
  const float* W = (which ? W2 : W1) + ((size_t)e << 20);
  ushort_t* Th = (which ? T2h : T1h) + ((size_t)e << 20);
  ushort_t* Tl = (which ? T2l : T1l) + ((size_t)e << 20);
  const int k0 = blockIdx.x << 5;
  const int n0 = blockIdx.y << 5;
  const int r = threadIdx.x >> 3;   // 0..31
  const int q = threadIdx.x & 7;    // 0..7
  float4 v = *(const float4*)(W + (size_t)(k0 + r) * HB + n0 + q * 4);
  sT[r][q*4+0] = v.x; sT[r][q*4+1] = v.y; sT[r][q*4+2] = v.z; sT[r][q*4+3] = v.w;
  __syncthreads();
  ushort_t hv[4], lv[4];
  #pragma unroll
  for (int j = 0; j < 4; ++j) {
    float f = sT[q*4+j][r];          // = W[k0+q*4+j][n0+r]
    ushort_t h = f2bf(f);
    hv[j] = h;
    lv[j] = f2bf(f - bf2f(h));
  }
  const size_t off = (size_t)(n0 + r) * HB + k0 + q * 4;
  ushort4 ph; ph.x = hv[0]; ph.y = hv[1]; ph.z = hv[2]; ph.w = hv[3];
  ushort4 pl; pl.x = lv[0]; pl.y = lv[1]; pl.z = lv[2]; pl.w = lv[3];
  *(ushort4*)(Th + off) = ph;
  *(ushort4*)(Tl + off) = pl;
}

// ---------------- router: softmax + top2 + expert lists ----------------
__global__ __launch_bounds__(256) void router_kernel(
    const float* __restrict__ X, const float* __restrict__ Wr, const float* __restrict__ br,
    float* __restrict__ wout, int* __restrict__ cnt,
    int* __restrict__ list, float* __restrict__ wlist)
{
  const int wid = threadIdx.x >> 6;
  const int lane = threadIdx.x & 63;
  const int t = blockIdx.x * 4 + wid;
  const float* xr = X + (size_t)t * HB;
  float p0=0,p1=0,p2=0,p3=0,p4=0,p5=0,p6=0,p7=0;
  for (int h0 = 0; h0 < HB; h0 += 64) {
    float xv = xr[h0 + lane];
    const float4 wa = *(const float4*)(Wr + (size_t)(h0 + lane) * NE);
    const float4 wb = *(const float4*)(Wr + (size_t)(h0 + lane) * NE + 4);
    p0 += xv * wa.x; p1 += xv * wa.y; p2 += xv * wa.z; p3 += xv * wa.w;
    p4 += xv * wb.x; p5 += xv * wb.y; p6 += xv * wb.z; p7 += xv * wb.w;
  }
  #pragma unroll
  for (int off = 1; off < 64; off <<= 1) {
    p0 += __shfl_xor(p0, off); p1 += __shfl_xor(p1, off);
    p2 += __shfl_xor(p2, off); p3 += __shfl_xor(p3, off);
    p4 += __shfl_xor(p4, off); p5 += __shfl_xor(p5, off);
    p6 += __shfl_xor(p6, off); p7 += __shfl_xor(p7, off);
  }
  if (lane == 0) {
    float w[8];
    w[0]=p0+br[0]; w[1]=p1+br[1]; w[2]=p2+br[2]; w[3]=p3+br[3];
    w[4]=p4+br[4]; w[5]=p5+br[5]; w[6]=p6+br[6]; w[7]=p7+br[7];
    float m = w[0];
    #pragma unroll
    for (int e = 1; e < 8; ++e) m = fmaxf(m, w[e]);
    float s = 0.f;
    #pragma unroll
    for (int e = 0; e < 8; ++e) { w[e] = expf(w[e] - m); s += w[e]; }
    const float inv = 1.f / s;
    #pragma unroll
    for (int e = 0; e < 8; ++e) w[e] *= inv;
    float4 w03; w03.x=w[0]; w03.y=w[1]; w03.z=w[2]; w03.w=w[3];
    float4 w47; w47.x=w[4]; w47.y=w[5]; w47.z=w[6]; w47.w=w[7];
    *(float4*)(wout + (size_t)t * NE)     = w03;
    *(float4*)(wout + (size_t)t * NE + 4) = w47;
    int i0 = 0; float v0 = w[0];
    #pragma unroll
    for (int e = 1; e < 8; ++e) if (w[e] > v0) { v0 = w[e]; i0 = e; }
    int i1 = -1; float v1 = -1.f;
    #pragma unroll
    for (int e = 0; e < 8; ++e) if (e != i0 && w[e] > v1) { v1 = w[e]; i1 = e; }
    const float rn = 1.f / (v0 + v1 + 1e-9f);
    int s0 = atomicAdd(&cnt[i0], 1);
    list[i0 * NB + s0] = t * 2;     wlist[i0 * NB + s0] = v0 * rn;
    int s1 = atomicAdd(&cnt[i1], 1);
    list[i1 * NB + s1] = t * 2 + 1; wlist[i1 * NB + s1] = v1 * rn;
  }
}

// ---------------- GEMM1: H1 = gelu(X @ W1 + b1), split-bf16 3-pass ----------------
__global__ __launch_bounds__(256) void gemm1_kernel(
    const float* __restrict__ X,
    const ushort_t* __restrict__ Wh, const ushort_t* __restrict__ Wl,
    const float* __restrict__ b1, const int* __restrict__ cnt, const int* __restrict__ list,
    ushort_t* __restrict__ H1h, ushort_t* __restrict__ H1l)
{
  const int e = blockIdx.z;
  const int ne = cnt[e];
  const int m0 = blockIdx.x * BM;
  if (m0 >= ne) return;
  const int n0 = blockIdx.y * BN;

  __shared__ short sAh[BM][PK], sAl[BM][PK], sBh[BN][PK], sBl[BN][PK];
  __shared__ int sId[BM];

  const int tid = threadIdx.x;
  if (tid < BM) {
    int idx = m0 + tid;
    sId[tid] = (idx < ne) ? list[e * NB + idx] : -1;
  }
  __syncthreads();

  const int srow = tid >> 1;       // staging row 0..127
  const int half = tid & 1;        // 32-wide k half
  const int rid  = sId[srow];
  const float* asrc = X + (size_t)(rid >> 1) * HB + half * 32;   // token row; valid iff rid>=0
  const ushort_t* bsrc_h = Wh + ((size_t)e << 20) + ((size_t)(n0 + srow) << 10) + half * 32;
  const ushort_t* bsrc_l = Wl + ((size_t)e << 20) + ((size_t)(n0 + srow) << 10) + half * 32;

  const int lane = tid & 63;
  const int wid  = tid >> 6;
  const int wr = wid >> 1, wc = wid & 1;
  const int lrow = lane & 15;
  const int lkg  = (lane >> 4) << 3;

  f32x4 acc[4][4];
  #pragma unroll
  for (int i = 0; i < 4; ++i)
    #pragma unroll
    for (int j = 0; j < 4; ++j) acc[i][j] = (f32x4){0.f, 0.f, 0.f, 0.f};

  for (int k0 = 0; k0 < HB; k0 += BK) {
    // stage A (fp32 -> hi/lo bf16)
    short* dh = &sAh[srow][half * 32];
    short* dl = &sAl[srow][half * 32];
    #pragma unroll
    for (int j = 0; j < 4; ++j) {
      bfx8 ph, pl;
      if (rid >= 0) {
        float4 va = *(const float4*)(asrc + k0 + j * 8);
        float4 vb = *(const float4*)(asrc + k0 + j * 8 + 4);
        float a[8] = {va.x, va.y, va.z, va.w, vb.x, vb.y, vb.z, vb.w};
        #pragma unroll
        for (int q = 0; q < 8; ++q) {
          ushort_t h = f2bf(a[q]);
          ph[q] = (short)h;
          pl[q] = (short)f2bf(a[q] - bf2f(h));
        }
      } else {
        #pragma unroll
        for (int q = 0; q < 8; ++q) { ph[q] = 0; pl[q] = 0; }
      }
      *(bfx8*)(dh + j * 8) = ph;
      *(bfx8*)(dl + j * 8) = pl;
    }
    // stage B (bf16 copy)
    #pragma unroll
    for (int j = 0; j < 4; ++j) {
      *(bfx8*)(&sBh[srow][half * 32 + j * 8]) = *(const bfx8*)(bsrc_h + k0 + j * 8);
      *(bfx8*)(&sBl[srow][half * 32 + j * 8]) = *(const bfx8*)(bsrc_l + k0 + j * 8);
    }
    __syncthreads();
    #pragma unroll
    for (int ks = 0; ks < 2; ++ks) {
      bfx8 ah[4], al[4], bh[4], bl[4];
      #pragma unroll
      for (int m = 0; m < 4; ++m) {
        ah[m] = *(const bfx8*)&sAh[wr * 64 + m * 16 + lrow][ks * 32 + lkg];
        al[m] = *(const bfx8*)&sAl[wr * 64 + m * 16 + lrow][ks * 32 + lkg];
      }
      #pragma unroll
      for (int n = 0; n < 4; ++n) {
        bh[n] = *(const bfx8*)&sBh[wc * 64 + n * 16 + lrow][ks * 32 + lkg];
        bl[n] = *(const bfx8*)&sBl[wc * 64 + n * 16 + lrow][ks * 32 + lkg];
      }
      #pragma unroll
      for (int m = 0; m < 4; ++m)
        #pragma unroll
        for (int n = 0; n < 4; ++n) {
          acc[m][n] = __builtin_amdgcn_mfma_f32_16x16x32_bf16(ah[m], bh[n], acc[m][n], 0, 0, 0);
          acc[m][n] = __builtin_amdgcn_mfma_f32_16x16x32_bf16(ah[m], bl[n], acc[m][n], 0, 0, 0);
          acc[m][n] = __builtin_amdgcn_mfma_f32_16x16x32_bf16(al[m], bh[n], acc[m][n], 0, 0, 0);
        }
    }
    __syncthreads();
  }

  const int rgrp = (lane >> 4) << 2;
  #pragma unroll
  for (int m = 0; m < 4; ++m)
    #pragma unroll
    for (int r = 0; r < 4; ++r) {
      const int row = wr * 64 + m * 16 + rgrp + r;
      const int orid = sId[row];
      if (orid < 0) continue;
      #pragma unroll
      for (int n = 0; n < 4; ++n) {
        const int col = n0 + wc * 64 + n * 16 + lrow;
        float v = acc[m][n][r] + b1[e * HB + col];
        v = gelu_exact(v);
        ushort_t h = f2bf(v);
        H1h[(size_t)orid * HB + col] = h;
        H1l[(size_t)orid * HB + col] = f2bf(v - bf2f(h));
      }
    }
}

// ---------------- GEMM2: OUTC = w * (H1 @ W2 + b2), split-bf16 3-pass ----------------
__global__ __launch_bounds__(256) void gemm2_kernel(
    const ushort_t* __restrict__ H1h, const ushort_t* __restrict__ H1l,
    const ushort_t* __restrict__ Wh, const ushort_t* __restrict__ Wl,
    const float* __restrict__ b2, const int* __restrict__ cnt, const int* __restrict__ list,
    const float* __restrict__ wlist, float* __restrict__ OUTC)
{
  const int e = blockIdx.z;
  const int ne = cnt[e];
  const int m0 = blockIdx.x * BM;
  if (m0 >= ne) return;
  const int n0 = blockIdx.y * BN;

  __shared__ short sAh[BM][PK], sAl[BM][PK], sBh[BN][PK], sBl[BN][PK];
  __shared__ int sId[BM];
  __shared__ float sWt[BM];

  const int tid = threadIdx.x;
  if (tid < BM) {
    int idx = m0 + tid;
    if (idx < ne) { sId[tid] = list[e * NB + idx]; sWt[tid] = wlist[e * NB + idx]; }
    else          { sId[tid] = -1;                 sWt[tid] = 0.f; }
  }
  __syncthreads();

  const int srow = tid >> 1;
  const int half = tid & 1;
  const int rid  = sId[srow];
  const ushort_t* ah_src = H1h + (size_t)rid * HB + half * 32;   // valid iff rid>=0
  const ushort_t* al_src = H1l + (size_t)rid * HB + half * 32;
  const ushort_t* bsrc_h = Wh + ((size_t)e << 20) + ((size_t)(n0 + srow) << 10) + half * 32;
  const ushort_t* bsrc_l = Wl + ((size_t)e << 20) + ((size_t)(n0 + srow) << 10) + half * 32;

  const int lane = tid & 63;
  const int wid  = tid >> 6;
  const int wr = wid >> 1, wc = wid & 1;
  const int lrow = lane & 15;
  const int lkg  = (lane >> 4) << 3;

  f32x4 acc[4][4];
  #pragma unroll
  for (int i = 0; i < 4; ++i)
    #pragma unroll
    for (int j = 0; j < 4; ++j) acc[i][j] = (f32x4){0.f, 0.f, 0.f, 0.f};

  for (int k0 = 0; k0 < HB; k0 += BK) {
    #pragma unroll
    for (int j = 0; j < 4; ++j) {
      bfx8 ph, pl;
      if (rid >= 0) {
        ph = *(const bfx8*)(ah_src + k0 + j * 8);
        pl = *(const bfx8*)(al_src + k0 + j * 8);
      } else {
        #pragma unroll
        for (int q = 0; q < 8; ++q) { ph[q] = 0; pl[q] = 0; }
      }
      *(bfx8*)(&sAh[srow][half * 32 + j * 8]) = ph;
      *(bfx8*)(&sAl[srow][half * 32 + j * 8]) = pl;
      *(bfx8*)(&sBh[srow][half * 32 + j * 8]) = *(const bfx8*)(bsrc_h + k0 + j * 8);
      *(bfx8*)(&sBl[srow][half * 32 + j * 8]) = *(const bfx8*)(bsrc_l + k0 + j * 8);
    }
    __syncthreads();
    #pragma unroll
    for (int ks = 0; ks < 2; ++ks) {
      bfx8 ah[4], al[4], bh[4], bl[4];
      #pragma unroll
      for (int m = 0; m < 4; ++m) {
        ah[m] = *(const bfx8*)&sAh[wr * 64 + m * 16 + lrow][ks * 32 + lkg];
        al[m] = *(const bfx8*)&sAl[wr * 64 + m * 16 + lrow][ks * 32 + lkg];
      }
      #pragma unroll
      for (int n = 0; n < 4; ++n) {
        bh[n] = *(const bfx8*)&sBh[wc * 64 + n * 16 + lrow][ks * 32 + lkg];
        bl[n] = *(const bfx8*)&sBl[wc * 64 + n * 16 + lrow][ks * 32 + lkg];
      }
      #pragma unroll
      for (int m = 0; m < 4; ++m)
        #pragma unroll
        for (int n = 0; n < 4; ++n) {
          acc[m][n] = __builtin_amdgcn_mfma_f32_16x16x32_bf16(ah[m], bh[n], acc[m][n], 0, 0, 0);
          acc[m][n] = __builtin_amdgcn_mfma_f32_16x16x32_bf16(ah[m], bl[n], acc[m][n], 0, 0, 0);
          acc[m][n] = __builtin_amdgcn_mfma_f32_16x16x32_bf16(al[m], bh[n], acc[m][n], 0, 0, 0);
        }
    }
    __syncthreads();
  }

  const int rgrp = (lane >> 4) << 2;
  #pragma unroll
  for (int m = 0; m < 4; ++m)
    #pragma unroll
    for (int r = 0; r < 4; ++r) {
      const int row = wr * 64 + m * 16 + rgrp + r;
      const int orid = sId[row];
      if (orid < 0) continue;
      const float wrow = sWt[row];
      #pragma unroll
      for (int n = 0; n < 4; ++n) {
        const int col = n0 + wc * 64 + n * 16 + lrow;
        OUTC[(size_t)orid * HB + col] = (acc[m][n][r] + b2[e * HB + col]) * wrow;
      }
    }
}

// ---------------- combine: out[t] = OUTC[t*2] + OUTC[t*2+1] ----------------
__global__ __launch_bounds__(256) void combine_kernel(
    const float* __restrict__ OUTC, float* __restrict__ out)
{
  const int i = blockIdx.x * 256 + threadIdx.x;   // float4 index over [NB][HB]
  const int t = i >> 8;                           // HB/4 = 256 float4 per row
  const int c4 = i & 255;
  const float4 a = *((const float4*)(OUTC + ((size_t)t << 11)) + c4);
  const float4 b = *((const float4*)(OUTC + ((size_t)t << 11) + HB) + c4);
  float4 o; o.x = a.x + b.x; o.y = a.y + b.y; o.z = a.z + b.z; o.w = a.w + b.w;
  *((float4*)out + i) = o;
}

extern "C" void kernel_launch(void* const* d_in, const int* in_sizes, int n_in,
                              void* d_out, int out_size, void* d_ws, size_t ws_size,
                              hipStream_t stream) {
  const float* X  = (const float*)d_in[0];
  const float* Wr = (const float*)d_in[1];
  const float* br = (const float*)d_in[2];
  const float* W1 = (const float*)d_in[3];
  const float* b1 = (const float*)d_in[4];
  const float* W2 = (const float*)d_in[5];
  const float* b2 = (const float*)d_in[6];
  float* out = (float*)d_out;

  char* ws = (char*)d_ws;
  size_t o = 0;
  int*      cnt   = (int*)(ws + o);      o += 256;
  int*      list  = (int*)(ws + o);      o += (size_t)NE * NB * 4;
  float*    wlist = (float*)(ws + o);    o += (size_t)NE * NB * 4;
  ushort_t* T1h   = (ushort_t*)(ws + o); o += (size_t)NE * HB * HB * 2;
  ushort_t* T1l   = (ushort_t*)(ws + o); o += (size_t)NE * HB * HB * 2;
  ushort_t* T2h   = (ushort_t*)(ws + o); o += (size_t)NE * HB * HB * 2;
  ushort_t* T2l   = (ushort_t*)(ws + o); o += (size_t)NE * HB * HB * 2;
  ushort_t* H1h   = (ushort_t*)(ws + o); o += (size_t)NB * 2 * HB * 2;
  ushort_t* H1l   = (ushort_t*)(ws + o); o += (size_t)NB * 2 * HB * 2;
  float*    OUTC  = (float*)(ws + o);    o += (size_t)NB * 2 * HB * 4;

  zero_cnt_kernel<<<1, 64, 0, stream>>>(cnt);
  wsplit_kernel<<<dim3(HB / 32, HB / 32, NE * 2), 256, 0, stream>>>(W1, W2, T1h, T1l, T2h, T2l);
  router_kernel<<<NB / 4, 256, 0, stream>>>(X, Wr, br, out + (size_t)NB * HB, cnt, list, wlist);
  gemm1_kernel<<<dim3(NB / BM, HB / BN, NE), 256, 0, stream>>>(X, T1h, T1l, b1, cnt, list, H1h, H1l);
  gemm2_kernel<<<dim3(NB / BM, HB / BN, NE), 256, 0, stream>>>(H1h, H1l, T2h, T2l, b2, cnt, list, wlist, OUTC);
  combine_kernel<<<NB * HB / 1024, 256, 0, stream>>>(OUTC, out);
}

// Round 2
// 711.812 us; speedup vs baseline: 1.3113x; 1.3113x over previous
//
#include <hip/hip_runtime.h>
#include <math.h>

// TinyMoE: B=8192 tokens, H=1024, E=8 experts, top_k=2.
// Sparse top-2 MoE. Split-bf16 (hi+lo, 3-pass) MFMA GEMMs for fp32-grade accuracy.
// Round 2: global_load_lds staging with XOR-swizzled per-lane source addresses
// (linear LDS dest), X pre-split once, all tiles bf16 at stage time.
// Outputs: combined [B,H] fp32 at d_out[0], weights [B,E] fp32 at d_out[B*H].

#define HB 1024
#define NB 8192
#define NE 8

#define BM 128
#define BN 128
#define BK 64

typedef unsigned short ushort_t;
typedef unsigned int u32;
typedef __attribute__((ext_vector_type(8))) short bfx8;
typedef __attribute__((ext_vector_type(4))) float f32x4;

__device__ __forceinline__ ushort_t f2bf(float f) {
  unsigned int x = __float_as_uint(f);
  x += 0x7fffu + ((x >> 16) & 1u);   // RTNE
  return (ushort_t)(x >> 16);
}
__device__ __forceinline__ float bf2f(ushort_t h) {
  return __uint_as_float(((unsigned int)h) << 16);
}
__device__ __forceinline__ float gelu_exact(float x) {
  return 0.5f * x * (1.0f + erff(x * 0.70710678118654752440f));
}
// global -> LDS direct copy, 16B per lane, 1KB per wave-call. LDS dest is
// wave-uniform base + lane*16 (linear); swizzle must be baked into the
// per-lane GLOBAL source address (rule 21).
__device__ __forceinline__ void gload16(const void* g, void* l) {
  __builtin_amdgcn_global_load_lds((const __attribute__((address_space(1))) u32*)g,
                                   (__attribute__((address_space(3))) u32*)l, 16, 0, 0);
}

// ---------------- zero counts ----------------
__global__ void zero_cnt_kernel(int* cnt) {
  if (threadIdx.x < NE) cnt[threadIdx.x] = 0;
}

// ---------------- X fp32 -> bf16 hi/lo split ----------------
__global__ __launch_bounds__(256) void xsplit_kernel(
    const float* __restrict__ X, ushort_t* __restrict__ Xh, ushort_t* __restrict__ Xl)
{
  const size_t i = ((size_t)blockIdx.x * 256 + threadIdx.x) * 8;
  float4 a = *(const float4*)(X + i);
  float4 b = *(const float4*)(X + i + 4);
  float f[8] = {a.x, a.y, a.z, a.w, b.x, b.y, b.z, b.w};
  bfx8 h, l;
  #pragma unroll
  for (int q = 0; q < 8; ++q) {
    ushort_t hh = f2bf(f[q]);
    h[q] = (short)hh;
    l[q] = (short)f2bf(f[q] - bf2f(hh));
  }
  *(bfx8*)(Xh + i) = h;
  *(bfx8*)(Xl + i) = l;
}

// ---------------- W transpose + bf16 hi/lo split ----------------
// W[e][k][n] fp32  ->  T[e][n][k] bf16 hi and lo (B-fragments read contiguous K).
__global__ __launch_bounds__(256) void wsplit_kernel(
    const float* __restrict__ W1, const float* __restrict__ W2,
    ushort_t* __restrict__ T1h, ushort_t* __restrict__ T1l,
    ushort_t* __restrict__ T2h, ushort_t* __restrict__ T2l)
{
  __shared__ float sT[32][33];
  const int e = blockIdx.z >> 1;
  const int which = blockIdx.z & 1;
  const float* W = (which ? W2 : W1) + ((size_t)e << 20);
  ushort_t* Th = (which ? T2h : T1h) + ((size_t)e << 20);
  ushort_t* Tl = (which ? T2l : T1l) + ((size_t)e << 20);
  const int k0 = blockIdx.x << 5;
  const int n0 = blockIdx.y << 5;
  const int r = threadIdx.x >> 3;   // 0..31
  const int q = threadIdx.x & 7;    // 0..7
  float4 v = *(const float4*)(W + (size_t)(k0 + r) * HB + n0 + q * 4);
  sT[r][q*4+0] = v.x; sT[r][q*4+1] = v.y; sT[r][q*4+2] = v.z; sT[r][q*4+3] = v.w;
  __syncthreads();
  ushort_t hv[4], lv[4];
  #pragma unroll
  for (int j = 0; j < 4; ++j) {
    float f = sT[q*4+j][r];          // = W[k0+q*4+j][n0+r]
    ushort_t h = f2bf(f);
    hv[j] = h;
    lv[j] = f2bf(f - bf2f(h));
  }
  const size_t off = (size_t)(n0 + r) * HB + k0 + q * 4;
  ushort4 ph; ph.x = hv[0]; ph.y = hv[1]; ph.z = hv[2]; ph.w = hv[3];
  ushort4 pl; pl.x = lv[0]; pl.y = lv[1]; pl.z = lv[2]; pl.w = lv[3];
  *(ushort4*)(Th + off) = ph;
  *(ushort4*)(Tl + off) = pl;
}

// ---------------- router: softmax + top2 + expert lists ----------------
__global__ __launch_bounds__(256) void router_kernel(
    const float* __restrict__ X, const float* __restrict__ Wr, const float* __restrict__ br,
    float* __restrict__ wout, int* __restrict__ cnt,
    int* __restrict__ list, float* __restrict__ wlist)
{
  const int wid = threadIdx.x >> 6;
  const int lane = threadIdx.x & 63;
  const int t = blockIdx.x * 4 + wid;
  const float* xr = X + (size_t)t * HB;
  float p0=0,p1=0,p2=0,p3=0,p4=0,p5=0,p6=0,p7=0;
  for (int h0 = 0; h0 < HB; h0 += 64) {
    float xv = xr[h0 + lane];
    const float4 wa = *(const float4*)(Wr + (size_t)(h0 + lane) * NE);
    const float4 wb = *(const float4*)(Wr + (size_t)(h0 + lane) * NE + 4);
    p0 += xv * wa.x; p1 += xv * wa.y; p2 += xv * wa.z; p3 += xv * wa.w;
    p4 += xv * wb.x; p5 += xv * wb.y; p6 += xv * wb.z; p7 += xv * wb.w;
  }
  #pragma unroll
  for (int off = 1; off < 64; off <<= 1) {
    p0 += __shfl_xor(p0, off); p1 += __shfl_xor(p1, off);
    p2 += __shfl_xor(p2, off); p3 += __shfl_xor(p3, off);
    p4 += __shfl_xor(p4, off); p5 += __shfl_xor(p5, off);
    p6 += __shfl_xor(p6, off); p7 += __shfl_xor(p7, off);
  }
  if (lane == 0) {
    float w[8];
    w[0]=p0+br[0]; w[1]=p1+br[1]; w[2]=p2+br[2]; w[3]=p3+br[3];
    w[4]=p4+br[4]; w[5]=p5+br[5]; w[6]=p6+br[6]; w[7]=p7+br[7];
    float m = w[0];
    #pragma unroll
    for (int e = 1; e < 8; ++e) m = fmaxf(m, w[e]);
    float s = 0.f;
    #pragma unroll
    for (int e = 0; e < 8; ++e) { w[e] = expf(w[e] - m); s += w[e]; }
    const float inv = 1.f / s;
    #pragma unroll
    for (int e = 0; e < 8; ++e) w[e] *= inv;
    float4 w03; w03.x=w[0]; w03.y=w[1]; w03.z=w[2]; w03.w=w[3];
    float4 w47; w47.x=w[4]; w47.y=w[5]; w47.z=w[6]; w47.w=w[7];
    *(float4*)(wout + (size_t)t * NE)     = w03;
    *(float4*)(wout + (size_t)t * NE + 4) = w47;
    int i0 = 0; float v0 = w[0];
    #pragma unroll
    for (int e = 1; e < 8; ++e) if (w[e] > v0) { v0 = w[e]; i0 = e; }
    int i1 = -1; float v1 = -1.f;
    #pragma unroll
    for (int e = 0; e < 8; ++e) if (e != i0 && w[e] > v1) { v1 = w[e]; i1 = e; }
    const float rn = 1.f / (v0 + v1 + 1e-9f);
    int s0 = atomicAdd(&cnt[i0], 1);
    list[i0 * NB + s0] = t * 2;     wlist[i0 * NB + s0] = v0 * rn;
    int s1 = atomicAdd(&cnt[i1], 1);
    list[i1 * NB + s1] = t * 2 + 1; wlist[i1 * NB + s1] = v1 * rn;
  }
}

// ---------------- GEMM1: H1 = gelu(X @ W1 + b1), split-bf16 3-pass ----------------
// All tiles staged via global_load_lds with XOR-swizzled per-lane source addresses.
// LDS layout: tile[row][slot^(row&7)] holds logical slot (8x16B slots per 128B row).
__global__ __launch_bounds__(256, 2) void gemm1_kernel(
    const ushort_t* __restrict__ Xh, const ushort_t* __restrict__ Xl,
    const ushort_t* __restrict__ Wh, const ushort_t* __restrict__ Wl,
    const float* __restrict__ b1, const int* __restrict__ cnt, const int* __restrict__ list,
    ushort_t* __restrict__ H1h, ushort_t* __restrict__ H1l)
{
  const int e = blockIdx.z;
  const int ne = cnt[e];
  const int m0 = blockIdx.x * BM;
  if (m0 >= ne) return;
  const int n0 = blockIdx.y * BN;

  __shared__ short sAh[BM][BK], sAl[BM][BK], sBh[BN][BK], sBl[BN][BK];
  __shared__ int sId[BM];

  const int tid = threadIdx.x;
  if (tid < BM) {
    int idx = m0 + tid;
    sId[tid] = (idx < ne) ? list[e * NB + idx] : -1;
  }
  __syncthreads();

  const int lane = tid & 63;
  const int w    = tid >> 6;
  const int rl    = lane >> 3;            // 0..7 row-in-chunk
  const int xslot = (lane & 7) ^ rl;      // XOR-swizzled source slot

  const ushort_t* srcAh[4]; const ushort_t* srcAl[4];
  const ushort_t* srcBh[4]; const ushort_t* srcBl[4];
  short* dAh[4]; short* dAl[4]; short* dBh[4]; short* dBl[4];
  #pragma unroll
  for (int c = 0; c < 4; ++c) {
    const int cr = w * 32 + c * 8 + rl;       // LDS row this lane stages
    const int rid = sId[cr];
    const size_t tok = (size_t)(rid < 0 ? 0 : (rid >> 1));
    srcAh[c] = Xh + (tok << 10) + xslot * 8;
    srcAl[c] = Xl + (tok << 10) + xslot * 8;
    const size_t nr = (size_t)(n0 + cr);
    srcBh[c] = Wh + ((size_t)e << 20) + (nr << 10) + xslot * 8;
    srcBl[c] = Wl + ((size_t)e << 20) + (nr << 10) + xslot * 8;
    dAh[c] = &sAh[w * 32 + c * 8][0];
    dAl[c] = &sAl[w * 32 + c * 8][0];
    dBh[c] = &sBh[w * 32 + c * 8][0];
    dBl[c] = &sBl[w * 32 + c * 8][0];
  }

  const int wr = w >> 1, wc = w & 1;
  const int lrow = lane & 15;
  const int sgrp = lane >> 4;     // 0..3 k-slot group
  const int xk   = lrow & 7;      // read-side XOR key (= row&7 for all fragment rows)

  f32x4 acc[4][4];
  #pragma unroll
  for (int i = 0; i < 4; ++i)
    #pragma unroll
    for (int j = 0; j < 4; ++j) acc[i][j] = (f32x4){0.f, 0.f, 0.f, 0.f};

  for (int k0 = 0; k0 < HB; k0 += BK) {
    #pragma unroll
    for (int c = 0; c < 4; ++c) {
      gload16(srcAh[c] + k0, dAh[c]);
      gload16(srcAl[c] + k0, dAl[c]);
      gload16(srcBh[c] + k0, dBh[c]);
      gload16(srcBl[c] + k0, dBl[c]);
    }
    __syncthreads();
    #pragma unroll
    for (int ks = 0; ks < 2; ++ks) {
      const int col = ((ks * 4 + sgrp) ^ xk) * 8;
      bfx8 ah[4], al[4], bh[4], bl[4];
      #pragma unroll
      for (int m = 0; m < 4; ++m) {
        const int row = wr * 64 + m * 16 + lrow;
        ah[m] = *(const bfx8*)&sAh[row][col];
        al[m] = *(const bfx8*)&sAl[row][col];
      }
      #pragma unroll
      for (int n = 0; n < 4; ++n) {
        const int row = wc * 64 + n * 16 + lrow;
        bh[n] = *(const bfx8*)&sBh[row][col];
        bl[n] = *(const bfx8*)&sBl[row][col];
      }
      #pragma unroll
      for (int m = 0; m < 4; ++m)
        #pragma unroll
        for (int n = 0; n < 4; ++n) {
          acc[m][n] = __builtin_amdgcn_mfma_f32_16x16x32_bf16(ah[m], bh[n], acc[m][n], 0, 0, 0);
          acc[m][n] = __builtin_amdgcn_mfma_f32_16x16x32_bf16(ah[m], bl[n], acc[m][n], 0, 0, 0);
          acc[m][n] = __builtin_amdgcn_mfma_f32_16x16x32_bf16(al[m], bh[n], acc[m][n], 0, 0, 0);
        }
    }
    __syncthreads();
  }

  const int rgrp = (lane >> 4) << 2;
  #pragma unroll
  for (int m = 0; m < 4; ++m)
    #pragma unroll
    for (int r = 0; r < 4; ++r) {
      const int row = wr * 64 + m * 16 + rgrp + r;
      const int orid = sId[row];
      if (orid < 0) continue;
      #pragma unroll
      for (int n = 0; n < 4; ++n) {
        const int col = n0 + wc * 64 + n * 16 + lrow;
        float v = acc[m][n][r] + b1[e * HB + col];
        v = gelu_exact(v);
        ushort_t h = f2bf(v);
        H1h[(size_t)orid * HB + col] = h;
        H1l[(size_t)orid * HB + col] = f2bf(v - bf2f(h));
      }
    }
}

// ---------------- GEMM2: OUTC = w * (H1 @ W2 + b2), split-bf16 3-pass ----------------
__global__ __launch_bounds__(256, 2) void gemm2_kernel(
    const ushort_t* __restrict__ H1h, const ushort_t* __restrict__ H1l,
    const ushort_t* __restrict__ Wh, const ushort_t* __restrict__ Wl,
    const float* __restrict__ b2, const int* __restrict__ cnt, const int* __restrict__ list,
    const float* __restrict__ wlist, float* __restrict__ OUTC)
{
  const int e = blockIdx.z;
  const int ne = cnt[e];
  const int m0 = blockIdx.x * BM;
  if (m0 >= ne) return;
  const int n0 = blockIdx.y * BN;

  __shared__ short sAh[BM][BK], sAl[BM][BK], sBh[BN][BK], sBl[BN][BK];
  __shared__ int sId[BM];
  __shared__ float sWt[BM];

  const int tid = threadIdx.x;
  if (tid < BM) {
    int idx = m0 + tid;
    if (idx < ne) { sId[tid] = list[e * NB + idx]; sWt[tid] = wlist[e * NB + idx]; }
    else          { sId[tid] = -1;                 sWt[tid] = 0.f; }
  }
  __syncthreads();

  const int lane = tid & 63;
  const int w    = tid >> 6;
  const int rl    = lane >> 3;
  const int xslot = (lane & 7) ^ rl;

  const ushort_t* srcAh[4]; const ushort_t* srcAl[4];
  const ushort_t* srcBh[4]; const ushort_t* srcBl[4];
  short* dAh[4]; short* dAl[4]; short* dBh[4]; short* dBl[4];
  #pragma unroll
  for (int c = 0; c < 4; ++c) {
    const int cr = w * 32 + c * 8 + rl;
    const int rid = sId[cr];
    const size_t rowid = (size_t)(rid < 0 ? 0 : rid);
    srcAh[c] = H1h + (rowid << 10) + xslot * 8;
    srcAl[c] = H1l + (rowid << 10) + xslot * 8;
    const size_t nr = (size_t)(n0 + cr);
    srcBh[c] = Wh + ((size_t)e << 20) + (nr << 10) + xslot * 8;
    srcBl[c] = Wl + ((size_t)e << 20) + (nr << 10) + xslot * 8;
    dAh[c] = &sAh[w * 32 + c * 8][0];
    dAl[c] = &sAl[w * 32 + c * 8][0];
    dBh[c] = &sBh[w * 32 + c * 8][0];
    dBl[c] = &sBl[w * 32 + c * 8][0];
  }

  const int wr = w >> 1, wc = w & 1;
  const int lrow = lane & 15;
  const int sgrp = lane >> 4;
  const int xk   = lrow & 7;

  f32x4 acc[4][4];
  #pragma unroll
  for (int i = 0; i < 4; ++i)
    #pragma unroll
    for (int j = 0; j < 4; ++j) acc[i][j] = (f32x4){0.f, 0.f, 0.f, 0.f};

  for (int k0 = 0; k0 < HB; k0 += BK) {
    #pragma unroll
    for (int c = 0; c < 4; ++c) {
      gload16(srcAh[c] + k0, dAh[c]);
      gload16(srcAl[c] + k0, dAl[c]);
      gload16(srcBh[c] + k0, dBh[c]);
      gload16(srcBl[c] + k0, dBl[c]);
    }
    __syncthreads();
    #pragma unroll
    for (int ks = 0; ks < 2; ++ks) {
      const int col = ((ks * 4 + sgrp) ^ xk) * 8;
      bfx8 ah[4], al[4], bh[4], bl[4];
      #pragma unroll
      for (int m = 0; m < 4; ++m) {
        const int row = wr * 64 + m * 16 + lrow;
        ah[m] = *(const bfx8*)&sAh[row][col];
        al[m] = *(const bfx8*)&sAl[row][col];
      }
      #pragma unroll
      for (int n = 0; n < 4; ++n) {
        const int row = wc * 64 + n * 16 + lrow;
        bh[n] = *(const bfx8*)&sBh[row][col];
        bl[n] = *(const bfx8*)&sBl[row][col];
      }
      #pragma unroll
      for (int m = 0; m < 4; ++m)
        #pragma unroll
        for (int n = 0; n < 4; ++n) {
          acc[m][n] = __builtin_amdgcn_mfma_f32_16x16x32_bf16(ah[m], bh[n], acc[m][n], 0, 0, 0);
          acc[m][n] = __builtin_amdgcn_mfma_f32_16x16x32_bf16(ah[m], bl[n], acc[m][n], 0, 0, 0);
          acc[m][n] = __builtin_amdgcn_mfma_f32_16x16x32_bf16(al[m], bh[n], acc[m][n], 0, 0, 0);
        }
    }
    __syncthreads();
  }

  const int rgrp = (lane >> 4) << 2;
  #pragma unroll
  for (int m = 0; m < 4; ++m)
    #pragma unroll
    for (int r = 0; r < 4; ++r) {
      const int row = wr * 64 + m * 16 + rgrp + r;
      const int orid = sId[row];
      if (orid < 0) continue;
      const float wrow = sWt[row];
      #pragma unroll
      for (int n = 0; n < 4; ++n) {
        const int col = n0 + wc * 64 + n * 16 + lrow;
        OUTC[(size_t)orid * HB + col] = (acc[m][n][r] + b2[e * HB + col]) * wrow;
      }
    }
}

// ---------------- combine: out[t] = OUTC[t*2] + OUTC[t*2+1] ----------------
__global__ __launch_bounds__(256) void combine_kernel(
    const float* __restrict__ OUTC, float* __restrict__ out)
{
  const int i = blockIdx.x * 256 + threadIdx.x;   // float4 index over [NB][HB]
  const int t = i >> 8;                           // HB/4 = 256 float4 per row
  const int c4 = i & 255;
  const float4 a = *((const float4*)(OUTC + ((size_t)t << 11)) + c4);
  const float4 b = *((const float4*)(OUTC + ((size_t)t << 11) + HB) + c4);
  float4 o; o.x = a.x + b.x; o.y = a.y + b.y; o.z = a.z + b.z; o.w = a.w + b.w;
  *((float4*)out + i) = o;
}

extern "C" void kernel_launch(void* const* d_in, const int* in_sizes, int n_in,
                              void* d_out, int out_size, void* d_ws, size_t ws_size,
                              hipStream_t stream) {
  const float* X  = (const float*)d_in[0];
  const float* Wr = (const float*)d_in[1];
  const float* br = (const float*)d_in[2];
  const float* W1 = (const float*)d_in[3];
  const float* b1 = (const float*)d_in[4];
  const float* W2 = (const float*)d_in[5];
  const float* b2 = (const float*)d_in[6];
  float* out = (float*)d_out;

  char* ws = (char*)d_ws;
  size_t o = 0;
  int*      cnt   = (int*)(ws + o);      o += 256;
  int*      list  = (int*)(ws + o);      o += (size_t)NE * NB * 4;
  float*    wlist = (float*)(ws + o);    o += (size_t)NE * NB * 4;
  ushort_t* T1h   = (ushort_t*)(ws + o); o += (size_t)NE * HB * HB * 2;
  ushort_t* T1l   = (ushort_t*)(ws + o); o += (size_t)NE * HB * HB * 2;
  ushort_t* T2h   = (ushort_t*)(ws + o); o += (size_t)NE * HB * HB * 2;
  ushort_t* T2l   = (ushort_t*)(ws + o); o += (size_t)NE * HB * HB * 2;
  ushort_t* H1h   = (ushort_t*)(ws + o); o += (size_t)NB * 2 * HB * 2;
  ushort_t* H1l   = (ushort_t*)(ws + o); o += (size_t)NB * 2 * HB * 2;
  // Region shared in time: Xh/Xl live only through gemm1; OUTC written by gemm2.
  char*     region = ws + o;             o += (size_t)NB * 2 * HB * 4;   // 64 MB
  ushort_t* Xh = (ushort_t*)region;                                      // 16 MB
  ushort_t* Xl = (ushort_t*)(region + (size_t)NB * HB * 2);              // 16 MB
  float*    OUTC = (float*)region;                                       // 64 MB (aliases Xh/Xl)

  zero_cnt_kernel<<<1, 64, 0, stream>>>(cnt);
  xsplit_kernel<<<NB * HB / (8 * 256), 256, 0, stream>>>(X, Xh, Xl);
  wsplit_kernel<<<dim3(HB / 32, HB / 32, NE * 2), 256, 0, stream>>>(W1, W2, T1h, T1l, T2h, T2l);
  router_kernel<<<NB / 4, 256, 0, stream>>>(X, Wr, br, out + (size_t)NB * HB, cnt, list, wlist);
  gemm1_kernel<<<dim3(NB / BM, HB / BN, NE), 256, 0, stream>>>(Xh, Xl, T1h, T1l, b1, cnt, list, H1h, H1l);
  gemm2_kernel<<<dim3(NB / BM, HB / BN, NE), 256, 0, stream>>>(H1h, H1l, T2h, T2l, b2, cnt, list, wlist, OUTC);
  combine_kernel<<<NB * HB / 1024, 256, 0, stream>>>(OUTC, out);
}

// Round 3
// 607.787 us; speedup vs baseline: 1.5357x; 1.1712x over previous
//
#include <hip/hip_runtime.h>
#include <math.h>

// TinyMoE: B=8192 tokens, H=1024, E=8 experts, top_k=2.
// Sparse top-2 MoE. Round 3: split-fp16 2-pass MFMA GEMMs (A = hi+lo fp16,
// B = fp16; error ~1e-4 abs, below the 1.95e-3 reference floor observed in
// rounds 1-2). 3 LDS tiles -> 48KB/block -> 3 blocks/CU implicit overlap.
// global_load_lds staging with XOR-swizzled per-lane source addresses.
// Outputs: combined [B,H] fp32 at d_out[0], weights [B,E] fp32 at d_out[B*H].

#define HB 1024
#define NB 8192
#define NE 8

#define BM 128
#define BN 128
#define BK 64

typedef unsigned short ushort_t;
typedef unsigned int u32;
typedef _Float16 f16;
typedef __attribute__((ext_vector_type(8))) _Float16 hfx8;
typedef __attribute__((ext_vector_type(4))) float f32x4;

__device__ __forceinline__ float gelu_exact(float x) {
  return 0.5f * x * (1.0f + erff(x * 0.70710678118654752440f));
}
// global -> LDS direct copy, 16B per lane, 1KB per wave-call. LDS dest is
// wave-uniform base + lane*16 (linear); swizzle is baked into the per-lane
// GLOBAL source address (rule 21: same involution on stage-source and read).
__device__ __forceinline__ void gload16(const void* g, void* l) {
  __builtin_amdgcn_global_load_lds((const __attribute__((address_space(1))) u32*)g,
                                   (__attribute__((address_space(3))) u32*)l, 16, 0, 0);
}

// ---------------- zero counts ----------------
__global__ void zero_cnt_kernel(int* cnt) {
  if (threadIdx.x < NE) cnt[threadIdx.x] = 0;
}

// ---------------- X fp32 -> fp16 hi/lo split ----------------
__global__ __launch_bounds__(256) void xsplit_kernel(
    const float* __restrict__ X, f16* __restrict__ Xh, f16* __restrict__ Xl)
{
  const size_t i = ((size_t)blockIdx.x * 256 + threadIdx.x) * 8;
  float4 a = *(const float4*)(X + i);
  float4 b = *(const float4*)(X + i + 4);
  float f[8] = {a.x, a.y, a.z, a.w, b.x, b.y, b.z, b.w};
  hfx8 h, l;
  #pragma unroll
  for (int q = 0; q < 8; ++q) {
    f16 hh = (f16)f[q];
    h[q] = hh;
    l[q] = (f16)(f[q] - (float)hh);
  }
  *(hfx8*)(Xh + i) = h;
  *(hfx8*)(Xl + i) = l;
}

// ---------------- W transpose + fp16 hi/lo split ----------------
// W[e][k][n] fp32  ->  T[e][n][k] fp16 hi and lo (B-fragments read contiguous K).
__global__ __launch_bounds__(256) void wsplit_kernel(
    const float* __restrict__ W1, const float* __restrict__ W2,
    f16* __restrict__ T1h, f16* __restrict__ T1l,
    f16* __restrict__ T2h, f16* __restrict__ T2l)
{
  __shared__ float sT[32][33];
  const int e = blockIdx.z >> 1;
  const int which = blockIdx.z & 1;
  const float* W = (which ? W2 : W1) + ((size_t)e << 20);
  f16* Th = (which ? T2h : T1h) + ((size_t)e << 20);
  f16* Tl = (which ? T2l : T1l) + ((size_t)e << 20);
  const int k0 = blockIdx.x << 5;
  const int n0 = blockIdx.y << 5;
  const int r = threadIdx.x >> 3;   // 0..31
  const int q = threadIdx.x & 7;    // 0..7
  float4 v = *(const float4*)(W + (size_t)(k0 + r) * HB + n0 + q * 4);
  sT[r][q*4+0] = v.x; sT[r][q*4+1] = v.y; sT[r][q*4+2] = v.z; sT[r][q*4+3] = v.w;
  __syncthreads();
  f16 hv[4], lv[4];
  #pragma unroll
  for (int j = 0; j < 4; ++j) {
    float f = sT[q*4+j][r];          // = W[k0+q*4+j][n0+r]
    f16 h = (f16)f;
    hv[j] = h;
    lv[j] = (f16)(f - (float)h);
  }
  const size_t off = (size_t)(n0 + r) * HB + k0 + q * 4;
  *(ushort4*)(Th + off) = *(ushort4*)hv;
  *(ushort4*)(Tl + off) = *(ushort4*)lv;
}

// ---------------- router: softmax + top2 + expert lists ----------------
__global__ __launch_bounds__(256) void router_kernel(
    const float* __restrict__ X, const float* __restrict__ Wr, const float* __restrict__ br,
    float* __restrict__ wout, int* __restrict__ cnt,
    int* __restrict__ list, float* __restrict__ wlist)
{
  const int wid = threadIdx.x >> 6;
  const int lane = threadIdx.x & 63;
  const int t = blockIdx.x * 4 + wid;
  const float* xr = X + (size_t)t * HB;
  float p0=0,p1=0,p2=0,p3=0,p4=0,p5=0,p6=0,p7=0;
  for (int h0 = 0; h0 < HB; h0 += 64) {
    float xv = xr[h0 + lane];
    const float4 wa = *(const float4*)(Wr + (size_t)(h0 + lane) * NE);
    const float4 wb = *(const float4*)(Wr + (size_t)(h0 + lane) * NE + 4);
    p0 += xv * wa.x; p1 += xv * wa.y; p2 += xv * wa.z; p3 += xv * wa.w;
    p4 += xv * wb.x; p5 += xv * wb.y; p6 += xv * wb.z; p7 += xv * wb.w;
  }
  #pragma unroll
  for (int off = 1; off < 64; off <<= 1) {
    p0 += __shfl_xor(p0, off); p1 += __shfl_xor(p1, off);
    p2 += __shfl_xor(p2, off); p3 += __shfl_xor(p3, off);
    p4 += __shfl_xor(p4, off); p5 += __shfl_xor(p5, off);
    p6 += __shfl_xor(p6, off); p7 += __shfl_xor(p7, off);
  }
  if (lane == 0) {
    float w[8];
    w[0]=p0+br[0]; w[1]=p1+br[1]; w[2]=p2+br[2]; w[3]=p3+br[3];
    w[4]=p4+br[4]; w[5]=p5+br[5]; w[6]=p6+br[6]; w[7]=p7+br[7];
    float m = w[0];
    #pragma unroll
    for (int e = 1; e < 8; ++e) m = fmaxf(m, w[e]);
    float s = 0.f;
    #pragma unroll
    for (int e = 0; e < 8; ++e) { w[e] = expf(w[e] - m); s += w[e]; }
    const float inv = 1.f / s;
    #pragma unroll
    for (int e = 0; e < 8; ++e) w[e] *= inv;
    float4 w03; w03.x=w[0]; w03.y=w[1]; w03.z=w[2]; w03.w=w[3];
    float4 w47; w47.x=w[4]; w47.y=w[5]; w47.z=w[6]; w47.w=w[7];
    *(float4*)(wout + (size_t)t * NE)     = w03;
    *(float4*)(wout + (size_t)t * NE + 4) = w47;
    int i0 = 0; float v0 = w[0];
    #pragma unroll
    for (int e = 1; e < 8; ++e) if (w[e] > v0) { v0 = w[e]; i0 = e; }
    int i1 = -1; float v1 = -1.f;
    #pragma unroll
    for (int e = 0; e < 8; ++e) if (e != i0 && w[e] > v1) { v1 = w[e]; i1 = e; }
    const float rn = 1.f / (v0 + v1 + 1e-9f);
    int s0 = atomicAdd(&cnt[i0], 1);
    list[i0 * NB + s0] = t * 2;     wlist[i0 * NB + s0] = v0 * rn;
    int s1 = atomicAdd(&cnt[i1], 1);
    list[i1 * NB + s1] = t * 2 + 1; wlist[i1 * NB + s1] = v1 * rn;
  }
}

// ---------------- GEMM1: H1 = gelu(X @ W1 + b1), split-fp16 2-pass ----------------
// Tiles staged via global_load_lds with XOR-swizzled per-lane source addresses.
// LDS layout: tile[row][slot^(row&7)] holds logical slot (8x16B slots per 128B row).
__global__ __launch_bounds__(256, 3) void gemm1_kernel(
    const f16* __restrict__ Xh, const f16* __restrict__ Xl,
    const f16* __restrict__ Wh,
    const float* __restrict__ b1, const int* __restrict__ cnt, const int* __restrict__ list,
    f16* __restrict__ H1h, f16* __restrict__ H1l)
{
  const int e = blockIdx.z;
  const int ne = cnt[e];
  const int m0 = blockIdx.x * BM;
  if (m0 >= ne) return;
  const int n0 = blockIdx.y * BN;

  __shared__ f16 sAh[BM][BK], sAl[BM][BK], sB[BN][BK];
  __shared__ int sId[BM];

  const int tid = threadIdx.x;
  if (tid < BM) {
    int idx = m0 + tid;
    sId[tid] = (idx < ne) ? list[e * NB + idx] : -1;
  }
  __syncthreads();

  const int lane = tid & 63;
  const int w    = tid >> 6;
  const int rl    = lane >> 3;            // 0..7 row-in-chunk
  const int xslot = (lane & 7) ^ rl;      // XOR-swizzled source slot

  const f16* srcAh[4]; const f16* srcAl[4]; const f16* srcB[4];
  f16* dAh[4]; f16* dAl[4]; f16* dB[4];
  #pragma unroll
  for (int c = 0; c < 4; ++c) {
    const int cr = w * 32 + c * 8 + rl;       // LDS row this lane stages
    const int rid = sId[cr];
    const size_t tok = (size_t)(rid < 0 ? 0 : (rid >> 1));
    srcAh[c] = Xh + (tok << 10) + xslot * 8;
    srcAl[c] = Xl + (tok << 10) + xslot * 8;
    const size_t nr = (size_t)(n0 + cr);
    srcB[c]  = Wh + ((size_t)e << 20) + (nr << 10) + xslot * 8;
    dAh[c] = &sAh[w * 32 + c * 8][0];
    dAl[c] = &sAl[w * 32 + c * 8][0];
    dB[c]  = &sB [w * 32 + c * 8][0];
  }

  const int wr = w >> 1, wc = w & 1;
  const int lrow = lane & 15;
  const int sgrp = lane >> 4;     // 0..3 k-slot group
  const int xk   = lrow & 7;      // read-side XOR key (= row&7 for all fragment rows)

  f32x4 acc[4][4];
  #pragma unroll
  for (int i = 0; i < 4; ++i)
    #pragma unroll
    for (int j = 0; j < 4; ++j) acc[i][j] = (f32x4){0.f, 0.f, 0.f, 0.f};

  for (int k0 = 0; k0 < HB; k0 += BK) {
    #pragma unroll
    for (int c = 0; c < 4; ++c) {
      gload16(srcAh[c] + k0, dAh[c]);
      gload16(srcAl[c] + k0, dAl[c]);
      gload16(srcB[c]  + k0, dB[c]);
    }
    __syncthreads();
    #pragma unroll
    for (int ks = 0; ks < 2; ++ks) {
      const int col = ((ks * 4 + sgrp) ^ xk) * 8;
      hfx8 ah[4], al[4], b[4];
      #pragma unroll
      for (int m = 0; m < 4; ++m) {
        const int row = wr * 64 + m * 16 + lrow;
        ah[m] = *(const hfx8*)&sAh[row][col];
        al[m] = *(const hfx8*)&sAl[row][col];
      }
      #pragma unroll
      for (int n = 0; n < 4; ++n) {
        const int row = wc * 64 + n * 16 + lrow;
        b[n] = *(const hfx8*)&sB[row][col];
      }
      #pragma unroll
      for (int m = 0; m < 4; ++m)
        #pragma unroll
        for (int n = 0; n < 4; ++n) {
          acc[m][n] = __builtin_amdgcn_mfma_f32_16x16x32_f16(ah[m], b[n], acc[m][n], 0, 0, 0);
          acc[m][n] = __builtin_amdgcn_mfma_f32_16x16x32_f16(al[m], b[n], acc[m][n], 0, 0, 0);
        }
    }
    __syncthreads();
  }

  const int rgrp = (lane >> 4) << 2;
  #pragma unroll
  for (int m = 0; m < 4; ++m)
    #pragma unroll
    for (int r = 0; r < 4; ++r) {
      const int row = wr * 64 + m * 16 + rgrp + r;
      const int orid = sId[row];
      if (orid < 0) continue;
      #pragma unroll
      for (int n = 0; n < 4; ++n) {
        const int col = n0 + wc * 64 + n * 16 + lrow;
        float v = acc[m][n][r] + b1[e * HB + col];
        v = gelu_exact(v);
        f16 h = (f16)v;
        H1h[(size_t)orid * HB + col] = h;
        H1l[(size_t)orid * HB + col] = (f16)(v - (float)h);
      }
    }
}

// ---------------- GEMM2: OUTC = w * (H1 @ W2 + b2), split-fp16 2-pass ----------------
__global__ __launch_bounds__(256, 3) void gemm2_kernel(
    const f16* __restrict__ H1h, const f16* __restrict__ H1l,
    const f16* __restrict__ Wh,
    const float* __restrict__ b2, const int* __restrict__ cnt, const int* __restrict__ list,
    const float* __restrict__ wlist, float* __restrict__ OUTC)
{
  const int e = blockIdx.z;
  const int ne = cnt[e];
  const int m0 = blockIdx.x * BM;
  if (m0 >= ne) return;
  const int n0 = blockIdx.y * BN;

  __shared__ f16 sAh[BM][BK], sAl[BM][BK], sB[BN][BK];
  __shared__ int sId[BM];
  __shared__ float sWt[BM];

  const int tid = threadIdx.x;
  if (tid < BM) {
    int idx = m0 + tid;
    if (idx < ne) { sId[tid] = list[e * NB + idx]; sWt[tid] = wlist[e * NB + idx]; }
    else          { sId[tid] = -1;                 sWt[tid] = 0.f; }
  }
  __syncthreads();

  const int lane = tid & 63;
  const int w    = tid >> 6;
  const int rl    = lane >> 3;
  const int xslot = (lane & 7) ^ rl;

  const f16* srcAh[4]; const f16* srcAl[4]; const f16* srcB[4];
  f16* dAh[4]; f16* dAl[4]; f16* dB[4];
  #pragma unroll
  for (int c = 0; c < 4; ++c) {
    const int cr = w * 32 + c * 8 + rl;
    const int rid = sId[cr];
    const size_t rowid = (size_t)(rid < 0 ? 0 : rid);
    srcAh[c] = H1h + (rowid << 10) + xslot * 8;
    srcAl[c] = H1l + (rowid << 10) + xslot * 8;
    const size_t nr = (size_t)(n0 + cr);
    srcB[c]  = Wh + ((size_t)e << 20) + (nr << 10) + xslot * 8;
    dAh[c] = &sAh[w * 32 + c * 8][0];
    dAl[c] = &sAl[w * 32 + c * 8][0];
    dB[c]  = &sB [w * 32 + c * 8][0];
  }

  const int wr = w >> 1, wc = w & 1;
  const int lrow = lane & 15;
  const int sgrp = lane >> 4;
  const int xk   = lrow & 7;

  f32x4 acc[4][4];
  #pragma unroll
  for (int i = 0; i < 4; ++i)
    #pragma unroll
    for (int j = 0; j < 4; ++j) acc[i][j] = (f32x4){0.f, 0.f, 0.f, 0.f};

  for (int k0 = 0; k0 < HB; k0 += BK) {
    #pragma unroll
    for (int c = 0; c < 4; ++c) {
      gload16(srcAh[c] + k0, dAh[c]);
      gload16(srcAl[c] + k0, dAl[c]);
      gload16(srcB[c]  + k0, dB[c]);
    }
    __syncthreads();
    #pragma unroll
    for (int ks = 0; ks < 2; ++ks) {
      const int col = ((ks * 4 + sgrp) ^ xk) * 8;
      hfx8 ah[4], al[4], b[4];
      #pragma unroll
      for (int m = 0; m < 4; ++m) {
        const int row = wr * 64 + m * 16 + lrow;
        ah[m] = *(const hfx8*)&sAh[row][col];
        al[m] = *(const hfx8*)&sAl[row][col];
      }
      #pragma unroll
      for (int n = 0; n < 4; ++n) {
        const int row = wc * 64 + n * 16 + lrow;
        b[n] = *(const hfx8*)&sB[row][col];
      }
      #pragma unroll
      for (int m = 0; m < 4; ++m)
        #pragma unroll
        for (int n = 0; n < 4; ++n) {
          acc[m][n] = __builtin_amdgcn_mfma_f32_16x16x32_f16(ah[m], b[n], acc[m][n], 0, 0, 0);
          acc[m][n] = __builtin_amdgcn_mfma_f32_16x16x32_f16(al[m], b[n], acc[m][n], 0, 0, 0);
        }
    }
    __syncthreads();
  }

  const int rgrp = (lane >> 4) << 2;
  #pragma unroll
  for (int m = 0; m < 4; ++m)
    #pragma unroll
    for (int r = 0; r < 4; ++r) {
      const int row = wr * 64 + m * 16 + rgrp + r;
      const int orid = sId[row];
      if (orid < 0) continue;
      const float wrow = sWt[row];
      #pragma unroll
      for (int n = 0; n < 4; ++n) {
        const int col = n0 + wc * 64 + n * 16 + lrow;
        OUTC[(size_t)orid * HB + col] = (acc[m][n][r] + b2[e * HB + col]) * wrow;
      }
    }
}

// ---------------- combine: out[t] = OUTC[t*2] + OUTC[t*2+1] ----------------
__global__ __launch_bounds__(256) void combine_kernel(
    const float* __restrict__ OUTC, float* __restrict__ out)
{
  const int i = blockIdx.x * 256 + threadIdx.x;   // float4 index over [NB][HB]
  const int t = i >> 8;                           // HB/4 = 256 float4 per row
  const int c4 = i & 255;
  const float4 a = *((const float4*)(OUTC + ((size_t)t << 11)) + c4);
  const float4 b = *((const float4*)(OUTC + ((size_t)t << 11) + HB) + c4);
  float4 o; o.x = a.x + b.x; o.y = a.y + b.y; o.z = a.z + b.z; o.w = a.w + b.w;
  *((float4*)out + i) = o;
}

extern "C" void kernel_launch(void* const* d_in, const int* in_sizes, int n_in,
                              void* d_out, int out_size, void* d_ws, size_t ws_size,
                              hipStream_t stream) {
  const float* X  = (const float*)d_in[0];
  const float* Wr = (const float*)d_in[1];
  const float* br = (const float*)d_in[2];
  const float* W1 = (const float*)d_in[3];
  const float* b1 = (const float*)d_in[4];
  const float* W2 = (const float*)d_in[5];
  const float* b2 = (const float*)d_in[6];
  float* out = (float*)d_out;

  char* ws = (char*)d_ws;
  size_t o = 0;
  int*   cnt   = (int*)(ws + o);   o += 256;
  int*   list  = (int*)(ws + o);   o += (size_t)NE * NB * 4;
  float* wlist = (float*)(ws + o); o += (size_t)NE * NB * 4;
  f16*   T1h   = (f16*)(ws + o);   o += (size_t)NE * HB * HB * 2;
  f16*   T1l   = (f16*)(ws + o);   o += (size_t)NE * HB * HB * 2;
  f16*   T2h   = (f16*)(ws + o);   o += (size_t)NE * HB * HB * 2;
  f16*   T2l   = (f16*)(ws + o);   o += (size_t)NE * HB * HB * 2;
  f16*   H1h   = (f16*)(ws + o);   o += (size_t)NB * 2 * HB * 2;
  f16*   H1l   = (f16*)(ws + o);   o += (size_t)NB * 2 * HB * 2;
  // Region shared in time: Xh/Xl live only through gemm1; OUTC written by gemm2.
  char*  region = ws + o;          o += (size_t)NB * 2 * HB * 4;   // 64 MB
  f16*   Xh = (f16*)region;                                        // 16 MB
  f16*   Xl = (f16*)(region + (size_t)NB * HB * 2);                // 16 MB
  float* OUTC = (float*)region;                                    // 64 MB (aliases Xh/Xl)

  zero_cnt_kernel<<<1, 64, 0, stream>>>(cnt);
  xsplit_kernel<<<NB * HB / (8 * 256), 256, 0, stream>>>(X, Xh, Xl);
  wsplit_kernel<<<dim3(HB / 32, HB / 32, NE * 2), 256, 0, stream>>>(W1, W2, T1h, T1l, T2h, T2l);
  router_kernel<<<NB / 4, 256, 0, stream>>>(X, Wr, br, out + (size_t)NB * HB, cnt, list, wlist);
  gemm1_kernel<<<dim3(NB / BM, HB / BN, NE), 256, 0, stream>>>(Xh, Xl, T1h, b1, cnt, list, H1h, H1l);
  gemm2_kernel<<<dim3(NB / BM, HB / BN, NE), 256, 0, stream>>>(H1h, H1l, T2h, b2, cnt, list, wlist, OUTC);
  combine_kernel<<<NB * HB / 1024, 256, 0, stream>>>(OUTC, out);
}

// Round 4
// 476.112 us; speedup vs baseline: 1.9604x; 1.2766x over previous
//
#include <hip/hip_runtime.h>
#include <math.h>

// TinyMoE: B=8192 tokens, H=1024, E=8 experts, top_k=2.
// Sparse top-2 MoE. Split-fp16 2-pass MFMA GEMMs (A = hi+lo fp16, B = fp16).
// Round 4: hierarchical router (LDS-aggregated counts, padded global counters)
// to kill the 198us same-cacheline atomic serialization; combine fused into
// gemm2 epilogue via 2-term deterministic fp32 atomicAdd; W-lo arrays dropped.
// Outputs: combined [B,H] fp32 at d_out[0], weights [B,E] fp32 at d_out[B*H].

#define HB 1024
#define NB 8192
#define NE 8
#define RTOK 16   // tokens per router block

#define BM 128
#define BN 128
#define BK 64

typedef unsigned short ushort_t;
typedef unsigned int u32;
typedef _Float16 f16;
typedef __attribute__((ext_vector_type(8))) _Float16 hfx8;
typedef __attribute__((ext_vector_type(4))) float f32x4;

__device__ __forceinline__ float gelu_exact(float x) {
  return 0.5f * x * (1.0f + erff(x * 0.70710678118654752440f));
}
// global -> LDS direct copy, 16B per lane, 1KB per wave-call. LDS dest is
// wave-uniform base + lane*16 (linear); swizzle is baked into the per-lane
// GLOBAL source address (rule 21: same involution on stage-source and read).
__device__ __forceinline__ void gload16(const void* g, void* l) {
  __builtin_amdgcn_global_load_lds((const __attribute__((address_space(1))) u32*)g,
                                   (__attribute__((address_space(3))) u32*)l, 16, 0, 0);
}

// ---------------- zero counts (padded: cnt[e*16]) ----------------
__global__ void zero_cnt_kernel(int* cnt) {
  if (threadIdx.x < NE * 16) cnt[threadIdx.x] = 0;
}

// ---------------- zero combined output ----------------
__global__ __launch_bounds__(256) void zero_out_kernel(float4* __restrict__ out) {
  out[(size_t)blockIdx.x * 256 + threadIdx.x] = (float4){0.f, 0.f, 0.f, 0.f};
}

// ---------------- X fp32 -> fp16 hi/lo split ----------------
__global__ __launch_bounds__(256) void xsplit_kernel(
    const float* __restrict__ X, f16* __restrict__ Xh, f16* __restrict__ Xl)
{
  const size_t i = ((size_t)blockIdx.x * 256 + threadIdx.x) * 8;
  float4 a = *(const float4*)(X + i);
  float4 b = *(const float4*)(X + i + 4);
  float f[8] = {a.x, a.y, a.z, a.w, b.x, b.y, b.z, b.w};
  hfx8 h, l;
  #pragma unroll
  for (int q = 0; q < 8; ++q) {
    f16 hh = (f16)f[q];
    h[q] = hh;
    l[q] = (f16)(f[q] - (float)hh);
  }
  *(hfx8*)(Xh + i) = h;
  *(hfx8*)(Xl + i) = l;
}

// ---------------- W transpose + fp16 (hi only) ----------------
// W[e][k][n] fp32  ->  T[e][n][k] fp16 (B-fragments read contiguous K).
__global__ __launch_bounds__(256) void wsplit_kernel(
    const float* __restrict__ W1, const float* __restrict__ W2,
    f16* __restrict__ T1h, f16* __restrict__ T2h)
{
  __shared__ float sT[32][33];
  const int e = blockIdx.z >> 1;
  const int which = blockIdx.z & 1;
  const float* W = (which ? W2 : W1) + ((size_t)e << 20);
  f16* Th = (which ? T2h : T1h) + ((size_t)e << 20);
  const int k0 = blockIdx.x << 5;
  const int n0 = blockIdx.y << 5;
  const int r = threadIdx.x >> 3;   // 0..31
  const int q = threadIdx.x & 7;    // 0..7
  float4 v = *(const float4*)(W + (size_t)(k0 + r) * HB + n0 + q * 4);
  sT[r][q*4+0] = v.x; sT[r][q*4+1] = v.y; sT[r][q*4+2] = v.z; sT[r][q*4+3] = v.w;
  __syncthreads();
  f16 hv[4];
  #pragma unroll
  for (int j = 0; j < 4; ++j) hv[j] = (f16)sT[q*4+j][r];   // = W[k0+q*4+j][n0+r]
  const size_t off = (size_t)(n0 + r) * HB + k0 + q * 4;
  *(ushort4*)(Th + off) = *(ushort4*)hv;
}

// ---------------- router: softmax + top2, hierarchical counting ----------------
// 512 blocks x 16 tokens. Per-block LDS counters -> one padded global atomic
// per expert per block (4096 total across 8 cachelines, vs 16384 on one line).
__global__ __launch_bounds__(256) void router_kernel(
    const float* __restrict__ X, const float* __restrict__ Wr, const float* __restrict__ br,
    float* __restrict__ wout, int* __restrict__ cnt,
    int* __restrict__ list, float* __restrict__ wlist)
{
  __shared__ int   sCnt[NE];
  __shared__ int   sBase[NE];
  __shared__ int   sE[RTOK][2];
  __shared__ int   sOff[RTOK][2];
  __shared__ float sW[RTOK][2];

  const int tid = threadIdx.x;
  if (tid < NE) sCnt[tid] = 0;
  __syncthreads();

  const int wv = tid >> 6;
  const int lane = tid & 63;

  for (int i = 0; i < 4; ++i) {
    const int s = wv * 4 + i;                 // token slot in block
    const int t = blockIdx.x * RTOK + s;
    const float* xr = X + (size_t)t * HB;
    float p0=0,p1=0,p2=0,p3=0,p4=0,p5=0,p6=0,p7=0;
    for (int h0 = 0; h0 < HB; h0 += 64) {
      float xv = xr[h0 + lane];
      const float4 wa = *(const float4*)(Wr + (size_t)(h0 + lane) * NE);
      const float4 wb = *(const float4*)(Wr + (size_t)(h0 + lane) * NE + 4);
      p0 += xv * wa.x; p1 += xv * wa.y; p2 += xv * wa.z; p3 += xv * wa.w;
      p4 += xv * wb.x; p5 += xv * wb.y; p6 += xv * wb.z; p7 += xv * wb.w;
    }
    #pragma unroll
    for (int off = 1; off < 64; off <<= 1) {
      p0 += __shfl_xor(p0, off); p1 += __shfl_xor(p1, off);
      p2 += __shfl_xor(p2, off); p3 += __shfl_xor(p3, off);
      p4 += __shfl_xor(p4, off); p5 += __shfl_xor(p5, off);
      p6 += __shfl_xor(p6, off); p7 += __shfl_xor(p7, off);
    }
    if (lane == 0) {
      float w[8];
      w[0]=p0+br[0]; w[1]=p1+br[1]; w[2]=p2+br[2]; w[3]=p3+br[3];
      w[4]=p4+br[4]; w[5]=p5+br[5]; w[6]=p6+br[6]; w[7]=p7+br[7];
      float m = w[0];
      #pragma unroll
      for (int e = 1; e < 8; ++e) m = fmaxf(m, w[e]);
      float sm = 0.f;
      #pragma unroll
      for (int e = 0; e < 8; ++e) { w[e] = expf(w[e] - m); sm += w[e]; }
      const float inv = 1.f / sm;
      #pragma unroll
      for (int e = 0; e < 8; ++e) w[e] *= inv;
      float4 w03; w03.x=w[0]; w03.y=w[1]; w03.z=w[2]; w03.w=w[3];
      float4 w47; w47.x=w[4]; w47.y=w[5]; w47.z=w[6]; w47.w=w[7];
      *(float4*)(wout + (size_t)t * NE)     = w03;
      *(float4*)(wout + (size_t)t * NE + 4) = w47;
      int i0 = 0; float v0 = w[0];
      #pragma unroll
      for (int e = 1; e < 8; ++e) if (w[e] > v0) { v0 = w[e]; i0 = e; }
      int i1 = -1; float v1 = -1.f;
      #pragma unroll
      for (int e = 0; e < 8; ++e) if (e != i0 && w[e] > v1) { v1 = w[e]; i1 = e; }
      const float rn = 1.f / (v0 + v1 + 1e-9f);
      const int o0 = atomicAdd(&sCnt[i0], 1);
      const int o1 = atomicAdd(&sCnt[i1], 1);
      sE[s][0] = i0; sOff[s][0] = o0; sW[s][0] = v0 * rn;
      sE[s][1] = i1; sOff[s][1] = o1; sW[s][1] = v1 * rn;
    }
  }
  __syncthreads();
  if (tid < NE) sBase[tid] = atomicAdd(&cnt[tid * 16], sCnt[tid]);
  __syncthreads();
  if (tid < RTOK * 2) {
    const int s = tid >> 1, j = tid & 1;
    const int t = blockIdx.x * RTOK + s;
    const int e = sE[s][j];
    const int pos = sBase[e] + sOff[s][j];
    list[e * NB + pos]  = t * 2 + j;
    wlist[e * NB + pos] = sW[s][j];
  }
}

// ---------------- GEMM1: H1 = gelu(X @ W1 + b1), split-fp16 2-pass ----------------
// Tiles staged via global_load_lds with XOR-swizzled per-lane source addresses.
// LDS layout: tile[row][slot^(row&7)] holds logical slot (8x16B slots per 128B row).
__global__ __launch_bounds__(256, 3) void gemm1_kernel(
    const f16* __restrict__ Xh, const f16* __restrict__ Xl,
    const f16* __restrict__ Wh,
    const float* __restrict__ b1, const int* __restrict__ cnt, const int* __restrict__ list,
    f16* __restrict__ H1h, f16* __restrict__ H1l)
{
  const int e = blockIdx.z;
  const int ne = cnt[e << 4];
  const int m0 = blockIdx.x * BM;
  if (m0 >= ne) return;
  const int n0 = blockIdx.y * BN;

  __shared__ f16 sAh[BM][BK], sAl[BM][BK], sB[BN][BK];
  __shared__ int sId[BM];

  const int tid = threadIdx.x;
  if (tid < BM) {
    int idx = m0 + tid;
    sId[tid] = (idx < ne) ? list[e * NB + idx] : -1;
  }
  __syncthreads();

  const int lane = tid & 63;
  const int w    = tid >> 6;
  const int rl    = lane >> 3;            // 0..7 row-in-chunk
  const int xslot = (lane & 7) ^ rl;      // XOR-swizzled source slot

  const f16* srcAh[4]; const f16* srcAl[4]; const f16* srcB[4];
  f16* dAh[4]; f16* dAl[4]; f16* dB[4];
  #pragma unroll
  for (int c = 0; c < 4; ++c) {
    const int cr = w * 32 + c * 8 + rl;       // LDS row this lane stages
    const int rid = sId[cr];
    const size_t tok = (size_t)(rid < 0 ? 0 : (rid >> 1));
    srcAh[c] = Xh + (tok << 10) + xslot * 8;
    srcAl[c] = Xl + (tok << 10) + xslot * 8;
    const size_t nr = (size_t)(n0 + cr);
    srcB[c]  = Wh + ((size_t)e << 20) + (nr << 10) + xslot * 8;
    dAh[c] = &sAh[w * 32 + c * 8][0];
    dAl[c] = &sAl[w * 32 + c * 8][0];
    dB[c]  = &sB [w * 32 + c * 8][0];
  }

  const int wr = w >> 1, wc = w & 1;
  const int lrow = lane & 15;
  const int sgrp = lane >> 4;     // 0..3 k-slot group
  const int xk   = lrow & 7;      // read-side XOR key (= row&7 for all fragment rows)

  f32x4 acc[4][4];
  #pragma unroll
  for (int i = 0; i < 4; ++i)
    #pragma unroll
    for (int j = 0; j < 4; ++j) acc[i][j] = (f32x4){0.f, 0.f, 0.f, 0.f};

  for (int k0 = 0; k0 < HB; k0 += BK) {
    #pragma unroll
    for (int c = 0; c < 4; ++c) {
      gload16(srcAh[c] + k0, dAh[c]);
      gload16(srcAl[c] + k0, dAl[c]);
      gload16(srcB[c]  + k0, dB[c]);
    }
    __syncthreads();
    #pragma unroll
    for (int ks = 0; ks < 2; ++ks) {
      const int col = ((ks * 4 + sgrp) ^ xk) * 8;
      hfx8 ah[4], al[4], b[4];
      #pragma unroll
      for (int m = 0; m < 4; ++m) {
        const int row = wr * 64 + m * 16 + lrow;
        ah[m] = *(const hfx8*)&sAh[row][col];
        al[m] = *(const hfx8*)&sAl[row][col];
      }
      #pragma unroll
      for (int n = 0; n < 4; ++n) {
        const int row = wc * 64 + n * 16 + lrow;
        b[n] = *(const hfx8*)&sB[row][col];
      }
      #pragma unroll
      for (int m = 0; m < 4; ++m)
        #pragma unroll
        for (int n = 0; n < 4; ++n) {
          acc[m][n] = __builtin_amdgcn_mfma_f32_16x16x32_f16(ah[m], b[n], acc[m][n], 0, 0, 0);
          acc[m][n] = __builtin_amdgcn_mfma_f32_16x16x32_f16(al[m], b[n], acc[m][n], 0, 0, 0);
        }
    }
    __syncthreads();
  }

  const int rgrp = (lane >> 4) << 2;
  #pragma unroll
  for (int m = 0; m < 4; ++m)
    #pragma unroll
    for (int r = 0; r < 4; ++r) {
      const int row = wr * 64 + m * 16 + rgrp + r;
      const int orid = sId[row];
      if (orid < 0) continue;
      #pragma unroll
      for (int n = 0; n < 4; ++n) {
        const int col = n0 + wc * 64 + n * 16 + lrow;
        float v = acc[m][n][r] + b1[e * HB + col];
        v = gelu_exact(v);
        f16 h = (f16)v;
        H1h[(size_t)orid * HB + col] = h;
        H1l[(size_t)orid * HB + col] = (f16)(v - (float)h);
      }
    }
}

// ---------------- GEMM2: out[tok] += w * (H1 @ W2 + b2), split-fp16 2-pass ----------
// Combine fused: each output element receives exactly 2 atomic adds (a+b == b+a
// in IEEE, so order-independent => deterministic). out must be pre-zeroed.
__global__ __launch_bounds__(256, 3) void gemm2_kernel(
    const f16* __restrict__ H1h, const f16* __restrict__ H1l,
    const f16* __restrict__ Wh,
    const float* __restrict__ b2, const int* __restrict__ cnt, const int* __restrict__ list,
    const float* __restrict__ wlist, float* __restrict__ out)
{
  const int e = blockIdx.z;
  const int ne = cnt[e << 4];
  const int m0 = blockIdx.x * BM;
  if (m0 >= ne) return;
  const int n0 = blockIdx.y * BN;

  __shared__ f16 sAh[BM][BK], sAl[BM][BK], sB[BN][BK];
  __shared__ int sId[BM];
  __shared__ float sWt[BM];

  const int tid = threadIdx.x;
  if (tid < BM) {
    int idx = m0 + tid;
    if (idx < ne) { sId[tid] = list[e * NB + idx]; sWt[tid] = wlist[e * NB + idx]; }
    else          { sId[tid] = -1;                 sWt[tid] = 0.f; }
  }
  __syncthreads();

  const int lane = tid & 63;
  const int w    = tid >> 6;
  const int rl    = lane >> 3;
  const int xslot = (lane & 7) ^ rl;

  const f16* srcAh[4]; const f16* srcAl[4]; const f16* srcB[4];
  f16* dAh[4]; f16* dAl[4]; f16* dB[4];
  #pragma unroll
  for (int c = 0; c < 4; ++c) {
    const int cr = w * 32 + c * 8 + rl;
    const int rid = sId[cr];
    const size_t rowid = (size_t)(rid < 0 ? 0 : rid);
    srcAh[c] = H1h + (rowid << 10) + xslot * 8;
    srcAl[c] = H1l + (rowid << 10) + xslot * 8;
    const size_t nr = (size_t)(n0 + cr);
    srcB[c]  = Wh + ((size_t)e << 20) + (nr << 10) + xslot * 8;
    dAh[c] = &sAh[w * 32 + c * 8][0];
    dAl[c] = &sAl[w * 32 + c * 8][0];
    dB[c]  = &sB [w * 32 + c * 8][0];
  }

  const int wr = w >> 1, wc = w & 1;
  const int lrow = lane & 15;
  const int sgrp = lane >> 4;
  const int xk   = lrow & 7;

  f32x4 acc[4][4];
  #pragma unroll
  for (int i = 0; i < 4; ++i)
    #pragma unroll
    for (int j = 0; j < 4; ++j) acc[i][j] = (f32x4){0.f, 0.f, 0.f, 0.f};

  for (int k0 = 0; k0 < HB; k0 += BK) {
    #pragma unroll
    for (int c = 0; c < 4; ++c) {
      gload16(srcAh[c] + k0, dAh[c]);
      gload16(srcAl[c] + k0, dAl[c]);
      gload16(srcB[c]  + k0, dB[c]);
    }
    __syncthreads();
    #pragma unroll
    for (int ks = 0; ks < 2; ++ks) {
      const int col = ((ks * 4 + sgrp) ^ xk) * 8;
      hfx8 ah[4], al[4], b[4];
      #pragma unroll
      for (int m = 0; m < 4; ++m) {
        const int row = wr * 64 + m * 16 + lrow;
        ah[m] = *(const hfx8*)&sAh[row][col];
        al[m] = *(const hfx8*)&sAl[row][col];
      }
      #pragma unroll
      for (int n = 0; n < 4; ++n) {
        const int row = wc * 64 + n * 16 + lrow;
        b[n] = *(const hfx8*)&sB[row][col];
      }
      #pragma unroll
      for (int m = 0; m < 4; ++m)
        #pragma unroll
        for (int n = 0; n < 4; ++n) {
          acc[m][n] = __builtin_amdgcn_mfma_f32_16x16x32_f16(ah[m], b[n], acc[m][n], 0, 0, 0);
          acc[m][n] = __builtin_amdgcn_mfma_f32_16x16x32_f16(al[m], b[n], acc[m][n], 0, 0, 0);
        }
    }
    __syncthreads();
  }

  const int rgrp = (lane >> 4) << 2;
  #pragma unroll
  for (int m = 0; m < 4; ++m)
    #pragma unroll
    for (int r = 0; r < 4; ++r) {
      const int row = wr * 64 + m * 16 + rgrp + r;
      const int orid = sId[row];
      if (orid < 0) continue;
      const float wrow = sWt[row];
      const size_t tok = (size_t)(orid >> 1);
      #pragma unroll
      for (int n = 0; n < 4; ++n) {
        const int col = n0 + wc * 64 + n * 16 + lrow;
        atomicAdd(&out[tok * HB + col], (acc[m][n][r] + b2[e * HB + col]) * wrow);
      }
    }
}

extern "C" void kernel_launch(void* const* d_in, const int* in_sizes, int n_in,
                              void* d_out, int out_size, void* d_ws, size_t ws_size,
                              hipStream_t stream) {
  const float* X  = (const float*)d_in[0];
  const float* Wr = (const float*)d_in[1];
  const float* br = (const float*)d_in[2];
  const float* W1 = (const float*)d_in[3];
  const float* b1 = (const float*)d_in[4];
  const float* W2 = (const float*)d_in[5];
  const float* b2 = (const float*)d_in[6];
  float* out = (float*)d_out;

  char* ws = (char*)d_ws;
  size_t o = 0;
  int*   cnt   = (int*)(ws + o);   o += 512;                       // padded: cnt[e*16]
  int*   list  = (int*)(ws + o);   o += (size_t)NE * NB * 4;
  float* wlist = (float*)(ws + o); o += (size_t)NE * NB * 4;
  f16*   T1h   = (f16*)(ws + o);   o += (size_t)NE * HB * HB * 2;  // 16 MB
  f16*   T2h   = (f16*)(ws + o);   o += (size_t)NE * HB * HB * 2;  // 16 MB
  f16*   H1h   = (f16*)(ws + o);   o += (size_t)NB * 2 * HB * 2;   // 32 MB
  f16*   H1l   = (f16*)(ws + o);   o += (size_t)NB * 2 * HB * 2;   // 32 MB
  f16*   Xh    = (f16*)(ws + o);   o += (size_t)NB * HB * 2;       // 16 MB
  f16*   Xl    = (f16*)(ws + o);   o += (size_t)NB * HB * 2;       // 16 MB

  zero_cnt_kernel<<<1, 128, 0, stream>>>(cnt);
  zero_out_kernel<<<NB * HB / 1024, 256, 0, stream>>>((float4*)out);
  xsplit_kernel<<<NB * HB / (8 * 256), 256, 0, stream>>>(X, Xh, Xl);
  wsplit_kernel<<<dim3(HB / 32, HB / 32, NE * 2), 256, 0, stream>>>(W1, W2, T1h, T2h);
  router_kernel<<<NB / RTOK, 256, 0, stream>>>(X, Wr, br, out + (size_t)NB * HB, cnt, list, wlist);
  gemm1_kernel<<<dim3(NB / BM, HB / BN, NE), 256, 0, stream>>>(Xh, Xl, T1h, b1, cnt, list, H1h, H1l);
  gemm2_kernel<<<dim3(NB / BM, HB / BN, NE), 256, 0, stream>>>(H1h, H1l, T2h, b2, cnt, list, wlist, out);
}